// Round 8
// baseline (385.834 us; speedup 1.0000x reference)
//
#include <hip/hip_runtime.h>
#include <hip/hip_bf16.h>

#define B 512
#define N 207
#define C 207
#define CO 512
#define NLAYERS 2
#define EPS 1e-5f

#define STRIDE 224      // padded inner dim (elements)
#define ROWS 208        // padded row count for H-class buffers
#define KSTEPS 7        // 224/32
#define RS ((size_t)ROWS*STRIDE)
#define XSTR 232        // X1/X2 LDS row stride (mult of 8; balanced bank spread)

typedef unsigned short ushort;
typedef short s8v __attribute__((ext_vector_type(8)));
typedef float f4 __attribute__((ext_vector_type(4)));
typedef unsigned short u16x4 __attribute__((ext_vector_type(4)));

__device__ __forceinline__ ushort f2bu(float f) {
    __hip_bfloat16 h = __float2bfloat16(f);
    return __builtin_bit_cast(ushort, h);
}
__device__ __forceinline__ float bu2f(ushort u) {
    union { unsigned int u; float f; } v; v.u = ((unsigned int)u) << 16;
    return v.f;
}
__device__ __forceinline__ u16x4 packbf4(f4 v) {
    u16x4 r;
    #pragma unroll
    for (int i = 0; i < 4; ++i) r[i] = f2bu(v[i]);
    return r;
}

// ---------------------------------------------------------------------------
// P1[w][v] = softmax_j(relu(nv1[w,:]@nv2[:,j]))[v]  (row-major, bf16, 224x224
// zero-padded). One block per row w.
// ---------------------------------------------------------------------------
__global__ void adp_kernel(const float* __restrict__ nv1, const float* __restrict__ nv2,
                           ushort* __restrict__ P1) {
    int w = blockIdx.x, j = threadIdx.x;
    __shared__ float red[256];
    if (w >= 207) {
        if (j < STRIDE) P1[w*STRIDE + j] = 0;
        return;
    }
    float val = 0.f;
    if (j < 207) {
        float acc = 0.f;
        #pragma unroll
        for (int k = 0; k < 10; ++k) acc += nv1[w*10 + k] * nv2[k*207 + j];
        val = fmaxf(acc, 0.f);
    }
    red[j] = (j < 207) ? val : -1e30f;
    __syncthreads();
    for (int off = 128; off > 0; off >>= 1) {
        if (j < off) red[j] = fmaxf(red[j], red[j+off]);
        __syncthreads();
    }
    float m = red[0];
    __syncthreads();
    float e = (j < 207) ? expf(val - m) : 0.f;
    red[j] = e;
    __syncthreads();
    for (int off = 128; off > 0; off >>= 1) {
        if (j < off) red[j] += red[j+off];
        __syncthreads();
    }
    float inv = 1.f / red[0];
    if (j < STRIDE) P1[w*STRIDE + j] = f2bu(e * inv);
}

// P2 = P1 @ P1
__global__ void p2_kernel(const ushort* __restrict__ P1, ushort* __restrict__ P2) {
    int v = blockIdx.x*16 + threadIdx.x;
    int w = blockIdx.y*16 + threadIdx.y;
    if (w < STRIDE && v < STRIDE) {
        float acc = 0.f;
        for (int u = 0; u < 207; ++u) acc += bu2f(P1[w*STRIDE + u]) * bu2f(P1[u*STRIDE + v]);
        P2[w*STRIDE + v] = f2bu(acc);
    }
}

// BN fold, padded: binv[o>=207]=0, bfold[o>=207]=0
__global__ void bn_kernel(const float* __restrict__ gamma, const float* __restrict__ beta,
                          const float* __restrict__ rmean, const float* __restrict__ rvar,
                          const float* __restrict__ bg,
                          float* __restrict__ binv, float* __restrict__ bfold) {
    int i = blockIdx.x*256 + threadIdx.x;
    if (i >= NLAYERS*ROWS) return;
    int l = i / ROWS, o = i % ROWS;
    float iv = 0.f, bf = 0.f;
    if (o < 207) {
        float g = gamma[l*207 + o];
        iv = g * rsqrtf(rvar[l*207 + o] + EPS);
        bf = bg[l*207 + o]*iv + beta[l*207 + o] - rmean[l*207 + o]*iv;
    }
    binv[i] = iv; bfold[i] = bf;
}

// Wg (L,207,621) f32 -> Wgp (L,3,208,224) bf16 zero-padded
__global__ void wg_prep(const float* __restrict__ Wg, ushort* __restrict__ Wgp) {
    int idx = blockIdx.x*256 + threadIdx.x;
    if (idx >= NLAYERS*3*ROWS*STRIDE) return;
    int k = idx % STRIDE;
    int o = (idx / STRIDE) % ROWS;
    int seg = (idx / (STRIDE*ROWS)) % 3;
    int l = idx / (STRIDE*ROWS*3);
    float v = (o < 207 && k < 207) ? Wg[((size_t)(l*207 + o))*621 + seg*207 + k] : 0.f;
    Wgp[idx] = f2bu(v);
}

// Wm (512,207) f32 -> Wmp (512,224) bf16 zero-padded
__global__ void wm_prep(const float* __restrict__ Wm, ushort* __restrict__ Wmp) {
    int idx = blockIdx.x*256 + threadIdx.x;
    if (idx >= CO*STRIDE) return;
    int k = idx % STRIDE, o = idx / STRIDE;
    Wmp[idx] = f2bu(k < 207 ? Wm[o*207 + k] : 0.f);
}

// x (B,207,207) f32 -> Hcv [c][n]  AND  Hnc [n][c]  (both 208x224, zero-padded)
__global__ void h0_kernel(const float* __restrict__ x, ushort* __restrict__ Hcv,
                          ushort* __restrict__ Hnc) {
    __shared__ float t[32][33];
    int b = blockIdx.z;
    int n0 = blockIdx.x*32, c0 = blockIdx.y*32;
    int tx = threadIdx.x, ty = threadIdx.y;
    for (int i = ty; i < 32; i += 8) {
        int n = n0 + i, c = c0 + tx;
        t[i][tx] = (n < 207 && c < 207) ? x[((size_t)b*207 + n)*207 + c] : 0.f;
    }
    __syncthreads();
    size_t base = (size_t)b*RS;
    for (int i = ty; i < 32; i += 8) {
        int n = n0 + i, c = c0 + tx;
        if (n < ROWS && c < STRIDE) Hnc[base + (size_t)n*STRIDE + c] = f2bu(t[i][tx]);
    }
    for (int i = ty; i < 32; i += 8) {
        int c = c0 + i, n = n0 + tx;
        if (c < ROWS && n < STRIDE) Hcv[base + (size_t)c*STRIDE + n] = f2bu(t[tx][i]);
    }
}

// ---------------------------------------------------------------------------
// async staging for 512-thread blocks: ROUNDS_*128 rows x 32 cols bf16 tile
// via global_load_lds (16B/lane, wave-uniform LDS base + lane*16B).
// rows clamped to rmax (clamped rows must be zero/benign rows in src).
// ---------------------------------------------------------------------------
template<int ROUNDS_>
__device__ __forceinline__ void stage512(ushort* __restrict__ tile,
                                         const ushort* __restrict__ src,
                                         int rbase, int rmax, int kbase, int tid) {
    int lane = tid & 63, wave = tid >> 6;   // 8 waves
    #pragma unroll
    for (int i = 0; i < ROUNDS_; ++i) {
        int r = rbase + i*128 + wave*16 + (lane >> 2);
        r = (r > rmax) ? rmax : r;
        const ushort* g = src + (size_t)r*STRIDE + kbase + (lane & 3)*8;
        ushort* l = tile + i*4096 + wave*512;          // wave-uniform base
        __builtin_amdgcn_global_load_lds(
            (const __attribute__((address_space(1))) void*)g,
            (__attribute__((address_space(3))) void*)l, 16, 0, 0);
    }
}

#define WAIT_VM(n) asm volatile("s_waitcnt vmcnt(" #n ")" ::: "memory")
#define WAIT_LGKM0 asm volatile("s_waitcnt lgkmcnt(0)" ::: "memory")

// ---------------------------------------------------------------------------
// layer_kernel: one block per (128-node slab, batch).
// Phase 1 (diffuse -> LDS): 3-buffer staging, prefetch 2 K-steps ahead.
// Phase 2 (gconv): 64o x 64n wave tiles; Hnc tiles pre-issued 7 steps early
//   into the dead X1 region; W double-buffered 1-deep (L2-resident).
// ---------------------------------------------------------------------------
__global__ __launch_bounds__(512, 2)
void layer_kernel(const ushort* __restrict__ Hcv, const ushort* __restrict__ Hnc,
                  const ushort* __restrict__ P1, const ushort* __restrict__ P2,
                  const ushort* __restrict__ Wgl,
                  const float* __restrict__ bi, const float* __restrict__ bsh,
                  ushort* __restrict__ Hcv_out, ushort* __restrict__ Hnc_out) {
    __shared__ __align__(16) ushort lds[75776];          // 148 KB
    // phase-1 staging (3-buffer), aliased over the (not yet written) X region:
    ushort* A1t = lds;                  // 3*4096 el
    ushort* A2t = lds + 12288;          // 3*4096 el
    ushort* Bt  = lds + 24576;          // 3*8192 el -> ends 49152
    ushort* Wgt = lds + 59392;          // 2*8192 el (256x32 dbuf)
    // phase-2 views:
    ushort* X1l = lds;                  // 128*XSTR = 29696 el
    ushort* X2l = lds + 29696;          // 29696 el
    ushort* Hnct = lds;                 // 7*4096 el over dead X1l (seg0 tiles)

    int tile = blockIdx.x;              // 0/1
    int b = blockIdx.y;
    int n0 = tile*128;
    size_t boff = (size_t)b*RS;
    const ushort* Hcvb = Hcv + boff;
    const ushort* Hncb = Hnc + boff;

    int tid = threadIdx.x, lane = tid & 63, wid = tid >> 6;
    int frow = lane & 15, fko = (lane >> 4)*8, g4 = (lane >> 4)*4;

    // ================= phase 1: diffuse into LDS =================
    int wmA = wid >> 1, wnA = wid & 1;   // wmA: 32 w-rows (2 frags); wnA: 128 c (8 frags)
    f4 aX1[2][8], aX2[2][8];
    #pragma unroll
    for (int i = 0; i < 2; ++i)
        #pragma unroll
        for (int j = 0; j < 8; ++j) { aX1[i][j] = (f4)0.f; aX2[i][j] = (f4)0.f; }

    // prologue: tiles 0 and 1
    #pragma unroll
    for (int t = 0; t < 2; ++t) {
        stage512<1>(A1t + t*4096, P1, n0, 223, t*32, tid);
        stage512<1>(A2t + t*4096, P2, n0, 223, t*32, tid);
        stage512<2>(Bt  + t*8192, Hcvb, 0, 207, t*32, tid);
    }

    for (int ks = 0; ks < KSTEPS; ++ks) {
        int bi3 = ks % 3;
        if (ks <= 4) {                      // stage tile ks+2 into buffer (ks+2)%3
            int t = ks + 2, b3 = t % 3;
            stage512<1>(A1t + b3*4096, P1, n0, 223, t*32, tid);
            stage512<1>(A2t + b3*4096, P2, n0, 223, t*32, tid);
            stage512<2>(Bt  + b3*8192, Hcvb, 0, 207, t*32, tid);
            WAIT_VM(8);                     // tile ks done; tiles ks+1,ks+2 in flight
        } else if (ks == 5) {
            stage512<2>(Wgt, Wgl + RS, 0, 207, 0, tid);   // phase-2 prologue (seg1,k=0)
            WAIT_VM(6);                     // tile 5 done; tile 6 + Wgt in flight
        } else {
            WAIT_VM(2);                     // tile 6 done; Wgt in flight
        }
        __builtin_amdgcn_s_barrier();
        s8v a1[2], a2[2], bfr[8];
        #pragma unroll
        for (int f = 0; f < 2; ++f) {
            a1[f] = *(const s8v*)&A1t[bi3*4096 + (wmA*32 + f*16 + frow)*32 + fko];
            a2[f] = *(const s8v*)&A2t[bi3*4096 + (wmA*32 + f*16 + frow)*32 + fko];
        }
        #pragma unroll
        for (int f = 0; f < 8; ++f)
            bfr[f] = *(const s8v*)&Bt[bi3*8192 + (wnA*128 + f*16 + frow)*32 + fko];
        #pragma unroll
        for (int fm = 0; fm < 2; ++fm)
            #pragma unroll
            for (int fn = 0; fn < 8; ++fn) {
                aX1[fm][fn] = __builtin_amdgcn_mfma_f32_16x16x32_bf16(bfr[fn], a1[fm], aX1[fm][fn], 0, 0, 0);
                aX2[fm][fn] = __builtin_amdgcn_mfma_f32_16x16x32_bf16(bfr[fn], a2[fm], aX2[fm][fn], 0, 0, 0);
            }
        WAIT_LGKM0;
        __builtin_amdgcn_s_barrier();
    }
    // phase-1 epilogue: X fragments -> LDS (staging regions now dead)
    #pragma unroll
    for (int fm = 0; fm < 2; ++fm) {
        int w = wmA*32 + fm*16 + (lane & 15);            // 0..127
        #pragma unroll
        for (int fn = 0; fn < 8; ++fn) {
            int cq = wnA*128 + fn*16 + g4;
            if (cq < STRIDE) {
                *(u16x4*)&X1l[w*XSTR + cq] = packbf4(aX1[fm][fn]);
                *(u16x4*)&X2l[w*XSTR + cq] = packbf4(aX2[fm][fn]);
            }
        }
    }
    WAIT_LGKM0;
    __builtin_amdgcn_s_barrier();

    // ================= phase 2: gconv (segs 1,2,0) =================
    int wmB = wid >> 1, wnB = wid & 1;   // wmB: 64 o-rows (4 frags); wnB: 64 n (4 frags)
    f4 aG[4][4];
    #pragma unroll
    for (int i = 0; i < 4; ++i)
        #pragma unroll
        for (int j = 0; j < 4; ++j) aG[i][j] = (f4)0.f;

    const int NK = 3*KSTEPS;
    for (int ks = 0; ks < NK; ++ks) {
        int cur = ks & 1;
        int seg = (ks < 7) ? 1 : (ks < 14) ? 2 : 0;
        int k0 = (ks % 7)*32;
        if (ks + 1 < NK) {
            int ks1 = ks + 1;
            int seg1v = (ks1 < 7) ? 1 : (ks1 < 14) ? 2 : 0;
            int kk1 = (ks1 % 7)*32;
            stage512<2>(Wgt + (cur^1)*8192, Wgl + (size_t)seg1v*RS, 0, 207, kk1, tid);
        }
        if (ks >= 7 && ks <= 13) {
            // pre-issue Hnc tile (ks-7) into dead X1 region; consumed at ks+7
            stage512<1>(Hnct + (ks-7)*4096, Hncb, n0, 207, (ks-7)*32, tid);
        }
        if (ks == NK-1) { WAIT_VM(0); }
        else if (ks >= 7 && ks <= 13) { WAIT_VM(3); }
        else { WAIT_VM(2); }
        __builtin_amdgcn_s_barrier();
        s8v a[4], bfr[4];
        #pragma unroll
        for (int f = 0; f < 4; ++f)
            a[f] = *(const s8v*)&Wgt[cur*8192 + (wmB*64 + f*16 + frow)*32 + fko];
        if (seg == 0) {
            const ushort* ht = Hnct + (ks - 14)*4096;
            #pragma unroll
            for (int fn = 0; fn < 4; ++fn)
                bfr[fn] = *(const s8v*)&ht[(wnB*64 + fn*16 + frow)*32 + fko];
        } else {
            const ushort* Xs = (seg == 1) ? X1l : X2l;
            #pragma unroll
            for (int fn = 0; fn < 4; ++fn) {
                int row = wnB*64 + fn*16 + frow;
                bfr[fn] = *(const s8v*)&Xs[row*XSTR + k0 + fko];
            }
        }
        #pragma unroll
        for (int fm = 0; fm < 4; ++fm)
            #pragma unroll
            for (int fn = 0; fn < 4; ++fn)
                aG[fm][fn] = __builtin_amdgcn_mfma_f32_16x16x32_bf16(bfr[fn], a[fm], aG[fm][fn], 0, 0, 0);
        WAIT_LGKM0;
        __builtin_amdgcn_s_barrier();
    }

    // phase-2 epilogue: BN fold + dual-layout store
    ushort* Ocv = Hcv_out + boff;
    ushort* Onc = Hnc_out + boff;
    #pragma unroll
    for (int fm = 0; fm < 4; ++fm) {
        int o = wmB*64 + fm*16 + (lane & 15);
        if (o >= ROWS) continue;
        float iv = bi[o], sh = bsh[o];                   // o==207 -> 0 -> zero row
        #pragma unroll
        for (int fn = 0; fn < 4; ++fn) {
            int nq = n0 + wnB*64 + fn*16 + g4;
            if (nq >= STRIDE) continue;
            f4 h = aG[fm][fn]*iv + sh;
            u16x4 hq = packbf4(h);
            *(u16x4*)(Ocv + (size_t)o*STRIDE + nq) = hq;
            #pragma unroll
            for (int r = 0; r < 4; ++r) {
                int n = nq + r;
                if (n < ROWS) Onc[(size_t)n*STRIDE + o] = hq[r];
            }
        }
    }
}

// ---------------------------------------------------------------------------
// final: out[b][n][o] = sum_c Hnc[n][c]*Wm[o][c] + bm[o]
// One block per (n-tile, batch): all 512 o columns, A (Hnc) staged once.
// ---------------------------------------------------------------------------
__global__ __launch_bounds__(512, 2)
void final_kernel(const ushort* __restrict__ Hnc, const ushort* __restrict__ Wmp,
                  const float* __restrict__ bm, float* __restrict__ out) {
    __shared__ __align__(16) ushort At[2][128*32], Bt[2][512*32];
    int b = blockIdx.y;
    int n0 = blockIdx.x*128;
    const ushort* Hb = Hnc + (size_t)b*RS;
    int tid = threadIdx.x, lane = tid & 63, wid = tid >> 6;
    int wo = wid >> 1, wn = wid & 1;
    int frow = lane & 15, fko = (lane >> 4)*8;

    f4 acc[4][8];
    #pragma unroll
    for (int i = 0; i < 4; ++i)
        #pragma unroll
        for (int j = 0; j < 8; ++j) acc[i][j] = (f4)0.f;

    stage512<1>(At[0], Hb,  n0, 207, 0, tid);
    stage512<4>(Bt[0], Wmp, 0, 511, 0, tid);

    for (int ks = 0; ks < KSTEPS; ++ks) {
        int cur = ks & 1;
        if (ks + 1 < KSTEPS) {
            int k1 = (ks + 1)*32;
            stage512<1>(At[cur^1], Hb,  n0, 207, k1, tid);
            stage512<4>(Bt[cur^1], Wmp, 0, 511, k1, tid);
            WAIT_VM(5);
        } else {
            WAIT_VM(0);
        }
        __builtin_amdgcn_s_barrier();
        s8v a[4], bf[8];
        #pragma unroll
        for (int f = 0; f < 4; ++f)
            a[f]  = *(const s8v*)&At[cur][(wn*64 + f*16 + frow)*32 + fko];
        #pragma unroll
        for (int f = 0; f < 8; ++f)
            bf[f] = *(const s8v*)&Bt[cur][(wo*128 + f*16 + frow)*32 + fko];
        #pragma unroll
        for (int fm = 0; fm < 4; ++fm)
            #pragma unroll
            for (int fn = 0; fn < 8; ++fn)
                acc[fm][fn] = __builtin_amdgcn_mfma_f32_16x16x32_bf16(bf[fn], a[fm], acc[fm][fn], 0, 0, 0);
        WAIT_LGKM0;
        __builtin_amdgcn_s_barrier();
    }

    int g4 = (lane >> 4)*4;
    #pragma unroll
    for (int fm = 0; fm < 4; ++fm) {
        int n = n0 + wn*64 + fm*16 + (lane & 15);
        if (n >= 207) continue;
        float* orow = out + ((size_t)b*207 + n)*CO;
        #pragma unroll
        for (int fn = 0; fn < 8; ++fn) {
            int oq = wo*128 + fn*16 + g4;           // < 512 always, 4-aligned
            f4 bias = *(const f4*)(bm + oq);
            f4 v = acc[fm][fn] + bias;
            *(f4*)(orow + oq) = v;
        }
    }
}

static inline size_t align_up(size_t v, size_t a) { return (v + a - 1) & ~(a - 1); }

extern "C" void kernel_launch(void* const* d_in, const int* in_sizes, int n_in,
                              void* d_out, int out_size, void* d_ws, size_t ws_size,
                              hipStream_t stream) {
    const float* x     = (const float*)d_in[0];
    const float* nv1   = (const float*)d_in[1];
    const float* nv2   = (const float*)d_in[2];
    const float* Wg    = (const float*)d_in[3];
    const float* bg    = (const float*)d_in[4];
    const float* gamma = (const float*)d_in[5];
    const float* beta  = (const float*)d_in[6];
    const float* rmean = (const float*)d_in[7];
    const float* rvar  = (const float*)d_in[8];
    const float* Wm    = (const float*)d_in[9];
    const float* bm    = (const float*)d_in[10];
    float* out = (float*)d_out;

    char* ws = (char*)d_ws;
    const size_t bufN = (size_t)B*RS*sizeof(ushort);   // 47.7 MB
    ushort* P1   = (ushort*)ws; ws += align_up((size_t)STRIDE*STRIDE*2, 512);
    ushort* P2   = (ushort*)ws; ws += align_up((size_t)STRIDE*STRIDE*2, 512);
    float* binv  = (float*)ws;  ws += align_up((size_t)NLAYERS*ROWS*4, 512);
    float* bfold = (float*)ws;  ws += align_up((size_t)NLAYERS*ROWS*4, 512);
    ushort* Wgp  = (ushort*)ws; ws += align_up((size_t)NLAYERS*3*RS*2, 512);
    ushort* Wmp  = (ushort*)ws; ws += align_up((size_t)CO*STRIDE*2, 512);
    ushort* A0 = (ushort*)ws; ws += align_up(bufN, 512);   // Hcv ping
    ushort* A1 = (ushort*)ws; ws += align_up(bufN, 512);   // Hnc ping
    ushort* B0 = (ushort*)ws; ws += align_up(bufN, 512);   // Hcv pong
    ushort* B1 = (ushort*)ws; ws += align_up(bufN, 512);   // Hnc pong

    // --- prep ---
    adp_kernel<<<STRIDE, 256, 0, stream>>>(nv1, nv2, P1);
    p2_kernel<<<dim3(14, 14), dim3(16, 16), 0, stream>>>(P1, P2);
    bn_kernel<<<(NLAYERS*ROWS + 255)/256, 256, 0, stream>>>(gamma, beta, rmean, rvar, bg, binv, bfold);
    wg_prep<<<(NLAYERS*3*ROWS*STRIDE + 255)/256, 256, 0, stream>>>(Wg, Wgp);
    wm_prep<<<(CO*STRIDE + 255)/256, 256, 0, stream>>>(Wm, Wmp);
    h0_kernel<<<dim3(7, 7, B), dim3(32, 8), 0, stream>>>(x, A0, A1);

    // --- layer 0 ---
    layer_kernel<<<dim3(2, B), 512, 0, stream>>>(A0, A1, P1, P2,
        Wgp, binv, bfold, B0, B1);
    // --- layer 1 ---
    layer_kernel<<<dim3(2, B), 512, 0, stream>>>(B0, B1, P1, P2,
        Wgp + (size_t)3*RS, binv + ROWS, bfold + ROWS, A0, A1);

    // --- final ---
    final_kernel<<<dim3(2, B), 512, 0, stream>>>(A1, Wmp, bm, out);
}